// Round 6
// baseline (432.244 us; speedup 1.0000x reference)
//
#include <hip/hip_runtime.h>
#include <hip/hip_fp16.h>

#define N_NODES  100000
#define N_EDGES  1600000
#define N_GRAPHS 64
#define NBUCK    391                 // ceil(N_NODES / 256)
#define NBLK     256
#define CHUNK    (N_EDGES / NBLK)    // 6250 exactly

// ---- workspace layout (int elements). No overlays: tmp and q are live
// simultaneously now. Total 3,701,760 ints = 14.8 MB.
#define OFF_GSTART 0            // 65 -> pad 128
#define OFF_DIS    128          // 100,000 -> pad 100,224
#define OFF_S      100224       // 200,000 (8B aligned) -> pad 300,288
#define OFF_QLO    300288       // 800,000 (100k x 8 half2, 16B aligned)
#define OFF_QHI    1100352      // 800,000
#define OFF_BHIST  1900544      // 100,096
#define OFF_BOFFL  2000640      // 100,096
#define OFF_BSUM   2100736      // 391 -> pad 512
#define OFF_BSTART 2101248      // 392 -> pad 512
#define OFF_TMP    2101760      // 1,600,000 -> ends 3,701,760

// ---------- scan helpers (block-uniform call sites only) ----------
__device__ __forceinline__ int excl_scan_256(int v, int* wsum) {
  int t = threadIdx.x, lane = t & 63, w = t >> 6;
  int x = v;
#pragma unroll
  for (int off = 1; off < 64; off <<= 1) {
    int y = __shfl_up(x, off, 64);
    if (lane >= off) x += y;
  }
  if (lane == 63) wsum[w] = x;
  __syncthreads();
  if (t == 0) {
    int r = 0;
#pragma unroll
    for (int i = 0; i < 4; ++i) { int tv = wsum[i]; wsum[i] = r; r += tv; }
  }
  __syncthreads();
  return x - v + wsum[w];
}

__device__ __forceinline__ int excl_scan_512(int v, int* wsum) {
  int t = threadIdx.x, lane = t & 63, w = t >> 6;
  int x = v;
#pragma unroll
  for (int off = 1; off < 64; off <<= 1) {
    int y = __shfl_up(x, off, 64);
    if (lane >= off) x += y;
  }
  if (lane == 63) wsum[w] = x;
  __syncthreads();
  if (t == 0) {
    int r = 0;
#pragma unroll
    for (int i = 0; i < 8; ++i) { int tv = wsum[i]; wsum[i] = r; r += tv; }
  }
  __syncthreads();
  return x - v + wsum[w];
}

// ---------- pass 1: per-block coarse histogram (LDS atomics only) ----------
__global__ void k_hist(const int* __restrict__ dst, int* __restrict__ bhist) {
  __shared__ int hist[NBUCK];
  int t = threadIdx.x, k = blockIdx.x;
  for (int b = t; b < NBUCK; b += 256) hist[b] = 0;
  __syncthreads();
  int e0 = k * CHUNK, e1 = e0 + CHUNK;
  for (int e = e0 + t; e < e1; e += 256) atomicAdd(&hist[dst[e] >> 8], 1);
  __syncthreads();
  for (int b = t; b < NBUCK; b += 256) bhist[b * NBLK + k] = hist[b];
}

// ---------- pass 2a: scan each bucket's per-block counts + graph bounds ----
__global__ void k_scan_a(const int* __restrict__ bhist, int* __restrict__ boffl,
                         int* __restrict__ bsum, const int* __restrict__ batch,
                         int* __restrict__ gstart) {
  __shared__ int wsum[4];
  int t = threadIdx.x, b = blockIdx.x;
  int i = b * 256 + t;
  if (i < N_NODES) {
    int bi = batch[i];
    if (i == 0) {
      for (int g = 0; g <= bi; ++g) gstart[g] = 0;
    } else {
      int bp = batch[i - 1];
      for (int g = bp + 1; g <= bi; ++g) gstart[g] = i;
    }
    if (i == N_NODES - 1) {
      for (int g = bi + 1; g <= N_GRAPHS; ++g) gstart[g] = N_NODES;
    }
  }
  int v = bhist[b * NBLK + t];
  int ex = excl_scan_256(v, wsum);
  boffl[b * NBLK + t] = ex;
  if (t == NBLK - 1) bsum[b] = ex + v;
}

// ---------- pass 2b: scan bucket totals -> bstart; zero pooled output ------
__global__ void k_scan_b(const int* __restrict__ bsum, int* __restrict__ bstart,
                         float* __restrict__ pooled) {
  __shared__ int wsum[8];
  int t = threadIdx.x;
  for (int i = t; i < N_GRAPHS * 32; i += 512) pooled[i] = 0.f;
  int v = (t < NBUCK) ? bsum[t] : 0;
  int ex = excl_scan_512(v, wsum);
  if (t <= NBUCK) bstart[t] = ex;
}

// ---------- pass 3: scatter edges into coarse buckets (LDS atomics only) ----
// tmp[pos] = (src << 8) | (dst & 255), grouped by dst-bucket
__global__ void k_scatter(const int* __restrict__ src, const int* __restrict__ dst,
                          const int* __restrict__ bstart, const int* __restrict__ boffl,
                          int* __restrict__ tmp) {
  __shared__ int sbase[NBUCK];
  __shared__ int fill[NBUCK];
  int t = threadIdx.x, k = blockIdx.x;
  for (int b = t; b < NBUCK; b += 256) {
    sbase[b] = bstart[b] + boffl[b * NBLK + k];
    fill[b] = 0;
  }
  __syncthreads();
  int e0 = k * CHUNK, e1 = e0 + CHUNK;
  for (int e = e0 + t; e < e1; e += 256) {
    int s_ = src[e], d_ = dst[e];
    int b = d_ >> 8;
    int pos = sbase[b] + atomicAdd(&fill[b], 1);
    tmp[pos] = (s_ << 8) | (d_ & 255);
  }
}

// ---------- pass 4: per-bucket degree histogram -> dis, s ------------------
__global__ void k_deg_s(const int* __restrict__ tmp, const int* __restrict__ bstart,
                        const float* __restrict__ x, float* __restrict__ dis,
                        float2* __restrict__ s) {
  __shared__ int hist[256];
  int t = threadIdx.x, b = blockIdx.x;
  int e0 = bstart[b], e1 = bstart[b + 1];
  hist[t] = 0;
  __syncthreads();
  for (int e = e0 + t; e < e1; e += 256) atomicAdd(&hist[tmp[e] & 255], 1);
  __syncthreads();
  int v = (b << 8) + t;
  if (v < N_NODES) {
    float dv = rsqrtf((float)(hist[t] + 1));
    dis[v] = dv;
    float2 xv = ((const float2*)x)[v];
    s[v] = make_float2(xv.x * dv, xv.y * dv);
  }
}

// ---------- layer 1, bucket-parallel: edge-parallel LDS aggregation of s,
// then thread-per-node MLP; q = fp16(dis * relu(t@W1+b1) @ W2) as two planes.
__global__ void k_layer1b(const int* __restrict__ tmp, const int* __restrict__ bstart,
                          const float2* __restrict__ s, const float* __restrict__ dis,
                          const float* __restrict__ W1, const float* __restrict__ b1,
                          const float* __restrict__ W2, int4* __restrict__ q_lo,
                          int4* __restrict__ q_hi) {
  __shared__ float accs[256 * 3];      // [dl*3 + c], pad-3 for bank spread
  __shared__ float4 sWB[64];           // {W1[0][j], W1[1][j], b1[j], 0}
  __shared__ float4 sW2[512];          // W2 row-major as float4
  int t = threadIdx.x, b = blockIdx.x;
  if (t < 64) sWB[t] = make_float4(W1[t], W1[64 + t], b1[t], 0.f);
  sW2[t] = ((const float4*)W2)[t];
  sW2[t + 256] = ((const float4*)W2)[t + 256];
  accs[t * 3] = 0.f;
  accs[t * 3 + 1] = 0.f;
  __syncthreads();
  int e0 = bstart[b], e1 = bstart[b + 1];
  for (int e = e0 + t; e < e1; e += 256) {
    int p = tmp[e];
    float2 su = s[p >> 8];
    int dl = p & 255;
    atomicAdd(&accs[dl * 3], su.x);
    atomicAdd(&accs[dl * 3 + 1], su.y);
  }
  __syncthreads();
  int v = (b << 8) + t;
  if (v >= N_NODES) return;
  float2 sself = s[v];
  float dv = dis[v];
  float t0 = (accs[t * 3] + sself.x) * dv;
  float t1 = (accs[t * 3 + 1] + sself.y) * dv;
  float4 a4[8];
#pragma unroll
  for (int m = 0; m < 8; ++m) a4[m] = make_float4(0.f, 0.f, 0.f, 0.f);
  for (int j = 0; j < 64; ++j) {
    float4 wb = sWB[j];
    float r = fmaxf(fmaf(t0, wb.x, fmaf(t1, wb.y, wb.z)), 0.f);
#pragma unroll
    for (int m = 0; m < 8; ++m) {
      float4 w = sW2[j * 8 + m];
      a4[m].x = fmaf(r, w.x, a4[m].x);
      a4[m].y = fmaf(r, w.y, a4[m].y);
      a4[m].z = fmaf(r, w.z, a4[m].z);
      a4[m].w = fmaf(r, w.w, a4[m].w);
    }
  }
  int pk[16];
#pragma unroll
  for (int m = 0; m < 8; ++m) {
    __half2 h0 = __floats2half2_rn(a4[m].x * dv, a4[m].y * dv);
    __half2 h1 = __floats2half2_rn(a4[m].z * dv, a4[m].w * dv);
    pk[2 * m]     = *reinterpret_cast<int*>(&h0);
    pk[2 * m + 1] = *reinterpret_cast<int*>(&h1);
  }
  q_lo[v * 2]     = make_int4(pk[0], pk[1], pk[2], pk[3]);
  q_lo[v * 2 + 1] = make_int4(pk[4], pk[5], pk[6], pk[7]);
  q_hi[v * 2]     = make_int4(pk[8], pk[9], pk[10], pk[11]);
  q_hi[v * 2 + 1] = make_int4(pk[12], pk[13], pk[14], pk[15]);
}

// ---------- layer 2 + pooling, bucket x plane blocks, XCD-partitioned ------
// block: plane h = (w&7)>>2 (XCD 0-3 -> lo, 4-7 -> hi), bucket b=(w>>3)*4+(w&3).
// Edge-parallel: 8 lanes/edge (half2 each), LDS float atomics into acc[256][17].
// Then per-node scale + self-term into 64x17 pool table; one flush per block.
__global__ void k_layer2b(const __half2* __restrict__ q_lo, const __half2* __restrict__ q_hi,
                          const int* __restrict__ tmp, const int* __restrict__ bstart,
                          const float* __restrict__ dis, const int* __restrict__ batch,
                          float* __restrict__ pooled) {
  __shared__ float acc[256 * 17];
  __shared__ float pool[64 * 17];
  int w = blockIdx.x;
  int h = (w & 7) >> 2;
  int b = (w >> 3) * 4 + (w & 3);
  if (b >= NBUCK) return;
  const __half2* q = h ? q_hi : q_lo;
  int t = threadIdx.x;
  for (int i = t; i < 256 * 17; i += 256) acc[i] = 0.f;
  for (int i = t; i < 64 * 17; i += 256) pool[i] = 0.f;
  __syncthreads();
  int e0 = bstart[b], e1 = bstart[b + 1];
  int lane = t & 7;            // half2 feature index within plane
  int eslot = t >> 3;          // 0..31
  for (int e = e0 + eslot; e < e1; e += 32) {
    int p = tmp[e];
    int u = p >> 8, dl = p & 255;
    float2 f = __half22float2(q[u * 8 + lane]);
    atomicAdd(&acc[dl * 17 + 2 * lane], f.x);
    atomicAdd(&acc[dl * 17 + 2 * lane + 1], f.y);
  }
  __syncthreads();
  int base_n = b << 8;
  int gmin = batch[base_n];
  int f = t & 15, ng = t >> 4;
  const __half* qh = (const __half*)q;
#pragma unroll 4
  for (int i = 0; i < 16; ++i) {
    int vl = ng * 16 + i;
    int v = base_n + vl;
    if (v < N_NODES) {
      float qself = __half2float(qh[v * 16 + f]);
      float val = (acc[vl * 17 + f] + qself) * dis[v];
      atomicAdd(&pool[(batch[v] - gmin) * 17 + f], val);
    }
  }
  __syncthreads();
  int gmax = batch[min(base_n + 255, N_NODES - 1)];
  int ngr = gmax - gmin + 1;
  for (int idx = t; idx < ngr * 16; idx += 256) {
    int gg = idx >> 4, ff = idx & 15;
    atomicAdd(&pooled[(gmin + gg) * 32 + h * 16 + ff], pool[gg * 17 + ff]);
  }
}

// ---------- final: mean + b2 ----------
__global__ void k_final(float* __restrict__ out, const int* __restrict__ gstart,
                        const float* __restrict__ b2) {
  int i = blockIdx.x * 256 + threadIdx.x;
  if (i < N_GRAPHS * 32) {
    int g = i >> 5, l = i & 31;
    int c = gstart[g + 1] - gstart[g];
    out[i] = (c > 0) ? out[i] / (float)c + b2[l] : 0.f;
  }
}

extern "C" void kernel_launch(void* const* d_in, const int* in_sizes, int n_in,
                              void* d_out, int out_size, void* d_ws, size_t ws_size,
                              hipStream_t stream) {
  (void)in_sizes; (void)n_in; (void)out_size; (void)ws_size;
  const float* x   = (const float*)d_in[0];
  const float* W1  = (const float*)d_in[1];
  const float* b1  = (const float*)d_in[2];
  const float* W2  = (const float*)d_in[3];
  const float* b2  = (const float*)d_in[4];
  const int* edge  = (const int*)d_in[5];
  const int* batch = (const int*)d_in[6];
  const int* src = edge;             // edge_index[0]
  const int* dst = edge + N_EDGES;   // edge_index[1]
  float* out = (float*)d_out;

  int* ws      = (int*)d_ws;
  int* gstart  = ws + OFF_GSTART;
  float* dis   = (float*)(ws + OFF_DIS);
  float2* s    = (float2*)(ws + OFF_S);
  int4* q_lo4  = (int4*)(ws + OFF_QLO);
  int4* q_hi4  = (int4*)(ws + OFF_QHI);
  int* bhist   = ws + OFF_BHIST;
  int* boffl   = ws + OFF_BOFFL;
  int* bsum    = ws + OFF_BSUM;
  int* bstart  = ws + OFF_BSTART;
  int* tmp     = ws + OFF_TMP;

  k_hist<<<NBLK, 256, 0, stream>>>(dst, bhist);
  k_scan_a<<<NBUCK, 256, 0, stream>>>(bhist, boffl, bsum, batch, gstart);
  k_scan_b<<<1, 512, 0, stream>>>(bsum, bstart, out);
  k_scatter<<<NBLK, 256, 0, stream>>>(src, dst, bstart, boffl, tmp);
  k_deg_s<<<NBUCK, 256, 0, stream>>>(tmp, bstart, x, dis, s);
  k_layer1b<<<NBUCK, 256, 0, stream>>>(tmp, bstart, s, dis, W1, b1, W2,
                                       q_lo4, q_hi4);
  const int n_wg2 = ((NBUCK + 3) / 4) * 8;   // 784
  k_layer2b<<<n_wg2, 256, 0, stream>>>((const __half2*)q_lo4, (const __half2*)q_hi4,
                                       tmp, bstart, dis, batch, out);
  k_final<<<8, 256, 0, stream>>>(out, gstart, b2);
}

// Round 7
// 113.590 us; speedup vs baseline: 3.8053x; 3.8053x over previous
//
#include <hip/hip_runtime.h>
#include <hip/hip_fp16.h>

#define N_NODES  100000
#define N_EDGES  1600000
#define N_GRAPHS 64
#define NBUCK    391                 // ceil(N_NODES / 256)
#define NBLK     256
#define CHUNK    (N_EDGES / NBLK)    // 6250 exactly
#define NODEBLK  1563                // ceil(N_NODES / 64)

// ---- workspace layout (int elements). q planes overlay the sort scratch,
// which is dead after k_fine. Max extent 3,802,112 ints = 15.2 MB.
#define OFF_GSTART 0            // 65 -> pad 128
#define OFF_ROWPTR 128          // 100,001 -> pad 100,096
#define OFF_DIS    100224       // 100,000 -> pad 100,096
#define OFF_S      200320       // 200,000 (8B aligned) -> pad 200,064
#define OFF_CSR    400384       // 1,600,000
#define OFF_QLO    2000384      // 800,000 ints (100k x 8 half2, 16B aligned)
#define OFF_QHI    2800512      // 800,000
#define OFF_BHIST  2000384      // overlays QLO (dead after k_scan_a)
#define OFF_BOFFL  2100736      // 100,352
#define OFF_BSUM   2201088      // 391 -> pad 512
#define OFF_BSTART 2201600      // 392 -> pad 512
#define OFF_TMP    2202112      // 1,600,000 (dead after k_fine)

// ---------- scan helpers (block-uniform call sites only) ----------
__device__ __forceinline__ int excl_scan_256(int v, int* wsum) {
  int t = threadIdx.x, lane = t & 63, w = t >> 6;
  int x = v;
#pragma unroll
  for (int off = 1; off < 64; off <<= 1) {
    int y = __shfl_up(x, off, 64);
    if (lane >= off) x += y;
  }
  if (lane == 63) wsum[w] = x;
  __syncthreads();
  if (t == 0) {
    int r = 0;
#pragma unroll
    for (int i = 0; i < 4; ++i) { int tv = wsum[i]; wsum[i] = r; r += tv; }
  }
  __syncthreads();
  return x - v + wsum[w];
}

__device__ __forceinline__ int excl_scan_512(int v, int* wsum) {
  int t = threadIdx.x, lane = t & 63, w = t >> 6;
  int x = v;
#pragma unroll
  for (int off = 1; off < 64; off <<= 1) {
    int y = __shfl_up(x, off, 64);
    if (lane >= off) x += y;
  }
  if (lane == 63) wsum[w] = x;
  __syncthreads();
  if (t == 0) {
    int r = 0;
#pragma unroll
    for (int i = 0; i < 8; ++i) { int tv = wsum[i]; wsum[i] = r; r += tv; }
  }
  __syncthreads();
  return x - v + wsum[w];
}

// ---------- pass 1: per-block coarse histogram (LDS atomics only) ----------
__global__ void k_hist(const int* __restrict__ dst, int* __restrict__ bhist) {
  __shared__ int hist[NBUCK];
  int t = threadIdx.x, k = blockIdx.x;
  for (int b = t; b < NBUCK; b += 256) hist[b] = 0;
  __syncthreads();
  int e0 = k * CHUNK, e1 = e0 + CHUNK;
  for (int e = e0 + t; e < e1; e += 256) atomicAdd(&hist[dst[e] >> 8], 1);
  __syncthreads();
  for (int b = t; b < NBUCK; b += 256) bhist[b * NBLK + k] = hist[b];
}

// ---------- pass 2a: scan each bucket's per-block counts + graph bounds ----
__global__ void k_scan_a(const int* __restrict__ bhist, int* __restrict__ boffl,
                         int* __restrict__ bsum, const int* __restrict__ batch,
                         int* __restrict__ gstart) {
  __shared__ int wsum[4];
  int t = threadIdx.x, b = blockIdx.x;
  int i = b * 256 + t;
  if (i < N_NODES) {
    int bi = batch[i];
    if (i == 0) {
      for (int g = 0; g <= bi; ++g) gstart[g] = 0;
    } else {
      int bp = batch[i - 1];
      for (int g = bp + 1; g <= bi; ++g) gstart[g] = i;
    }
    if (i == N_NODES - 1) {
      for (int g = bi + 1; g <= N_GRAPHS; ++g) gstart[g] = N_NODES;
    }
  }
  int v = bhist[b * NBLK + t];
  int ex = excl_scan_256(v, wsum);
  boffl[b * NBLK + t] = ex;
  if (t == NBLK - 1) bsum[b] = ex + v;
}

// ---------- pass 2b: scan bucket totals -> bstart; zero pooled output ------
__global__ void k_scan_b(const int* __restrict__ bsum, int* __restrict__ bstart,
                         float* __restrict__ pooled) {
  __shared__ int wsum[8];
  int t = threadIdx.x;
  for (int i = t; i < N_GRAPHS * 32; i += 512) pooled[i] = 0.f;
  int v = (t < NBUCK) ? bsum[t] : 0;
  int ex = excl_scan_512(v, wsum);
  if (t <= NBUCK) bstart[t] = ex;
}

// ---------- pass 3: scatter edges into coarse buckets (LDS atomics only) ----
__global__ void k_scatter(const int* __restrict__ src, const int* __restrict__ dst,
                          const int* __restrict__ bstart, const int* __restrict__ boffl,
                          int* __restrict__ tmp) {
  __shared__ int sbase[NBUCK];
  __shared__ int fill[NBUCK];
  int t = threadIdx.x, k = blockIdx.x;
  for (int b = t; b < NBUCK; b += 256) {
    sbase[b] = bstart[b] + boffl[b * NBLK + k];
    fill[b] = 0;
  }
  __syncthreads();
  int e0 = k * CHUNK, e1 = e0 + CHUNK;
  for (int e = e0 + t; e < e1; e += 256) {
    int s_ = src[e], d_ = dst[e];
    int b = d_ >> 8;
    int pos = sbase[b] + atomicAdd(&fill[b], 1);
    tmp[pos] = (s_ << 8) | (d_ & 255);
  }
}

// ---------- pass 4: per-bucket fine CSR + dis + s (LDS atomics only) -------
__global__ void k_fine(const int* __restrict__ tmp, const int* __restrict__ bstart,
                       const float* __restrict__ x, int* __restrict__ csr_src,
                       int* __restrict__ row_ptr, float* __restrict__ dis,
                       float2* __restrict__ s) {
  __shared__ int hist[256];   // becomes scanned offsets after scan
  __shared__ int fill[256];
  __shared__ int wsum[4];
  int t = threadIdx.x, b = blockIdx.x;
  int base_n = b << 8;
  int e0 = bstart[b], e1 = bstart[b + 1];
  hist[t] = 0;
  __syncthreads();
  for (int e = e0 + t; e < e1; e += 256) atomicAdd(&hist[tmp[e] & 255], 1);
  __syncthreads();
  int h = hist[t];
  int ex = excl_scan_256(h, wsum);
  hist[t] = ex;
  fill[t] = 0;
  int nn = min(256, N_NODES - base_n);
  if (t < nn) {
    int v = base_n + t;
    row_ptr[v] = e0 + ex;
    float dv = rsqrtf((float)(h + 1));
    dis[v] = dv;
    float2 xv = ((const float2*)x)[v];
    s[v] = make_float2(xv.x * dv, xv.y * dv);
  }
  if (b == NBUCK - 1 && t == 0) row_ptr[N_NODES] = e1;
  __syncthreads();
  for (int e = e0 + t; e < e1; e += 256) {
    int p = tmp[e];
    int fine = p & 255;
    int pos = e0 + hist[fine] + atomicAdd(&fill[fine], 1);
    csr_src[pos] = p >> 8;
  }
}

// ---------- layer 1 fused: t = dis*(sum s + self); q = fp16(dis*relu(t@W1+b1)@W2)
// weights as float4 LDS broadcasts (proven best config, R3/R4 bench)
__global__ void k_layer1(const float2* __restrict__ s, const float* __restrict__ dis,
                         const int* __restrict__ row_ptr, const int* __restrict__ csr_src,
                         const float* __restrict__ W1, const float* __restrict__ b1,
                         const float* __restrict__ W2, int4* __restrict__ q_lo,
                         int4* __restrict__ q_hi) {
  __shared__ float4 sWB[64];     // {W1[0][j], W1[1][j], b1[j], 0}
  __shared__ float4 sW2[512];    // W2 row-major as float4
  int tid = threadIdx.x;
  if (tid < 64) sWB[tid] = make_float4(W1[tid], W1[64 + tid], b1[tid], 0.f);
  for (int i = tid; i < 512; i += 256) sW2[i] = ((const float4*)W2)[i];
  __syncthreads();
  int v = blockIdx.x * 256 + tid;
  if (v >= N_NODES) return;
  int beg = row_ptr[v], end = row_ptr[v + 1];
  float2 sv = s[v];
  float t0 = sv.x, t1 = sv.y;
  int k = beg;
  for (; k + 4 <= end; k += 4) {
    int u0 = csr_src[k], u1 = csr_src[k + 1], u2 = csr_src[k + 2], u3 = csr_src[k + 3];
    float2 a = s[u0], b = s[u1], c = s[u2], d = s[u3];
    t0 += (a.x + b.x) + (c.x + d.x);
    t1 += (a.y + b.y) + (c.y + d.y);
  }
  for (; k < end; ++k) {
    float2 su = s[csr_src[k]];
    t0 += su.x;
    t1 += su.y;
  }
  float dv = dis[v];
  t0 *= dv;
  t1 *= dv;
  float4 a4[8];
#pragma unroll
  for (int m = 0; m < 8; ++m) a4[m] = make_float4(0.f, 0.f, 0.f, 0.f);
  for (int j = 0; j < 64; ++j) {
    float4 wb = sWB[j];
    float r = fmaxf(fmaf(t0, wb.x, fmaf(t1, wb.y, wb.z)), 0.f);
#pragma unroll
    for (int m = 0; m < 8; ++m) {
      float4 w = sW2[j * 8 + m];
      a4[m].x = fmaf(r, w.x, a4[m].x);
      a4[m].y = fmaf(r, w.y, a4[m].y);
      a4[m].z = fmaf(r, w.z, a4[m].z);
      a4[m].w = fmaf(r, w.w, a4[m].w);
    }
  }
  int pk[16];
#pragma unroll
  for (int m = 0; m < 8; ++m) {
    __half2 h0 = __floats2half2_rn(a4[m].x * dv, a4[m].y * dv);
    __half2 h1 = __floats2half2_rn(a4[m].z * dv, a4[m].w * dv);
    pk[2 * m]     = *reinterpret_cast<int*>(&h0);
    pk[2 * m + 1] = *reinterpret_cast<int*>(&h1);
  }
  q_lo[v * 2]     = make_int4(pk[0], pk[1], pk[2], pk[3]);
  q_lo[v * 2 + 1] = make_int4(pk[4], pk[5], pk[6], pk[7]);
  q_hi[v * 2]     = make_int4(pk[8], pk[9], pk[10], pk[11]);
  q_hi[v * 2 + 1] = make_int4(pk[12], pk[13], pk[14], pk[15]);
}

// ---------- layer 2 + pooling, XCD-partitioned feature halves --------------
// wg w: plane h = (w&7)>>2 (XCDs 0-3 -> lo, 4-7 -> hi); sub = (w>>3)*4+(w&3)
// covers 64 nodes. 512 threads: 64 rowgroups x 8 lanes, ONE node per rowgroup
// (minimal serial chain). Software-pipelined index prefetch: next 8 indices
// issued before current q-loads are consumed.
__global__ void __launch_bounds__(512)
k_layer2(const __half2* __restrict__ q_lo, const __half2* __restrict__ q_hi,
         const float* __restrict__ dis, const int* __restrict__ row_ptr,
         const int* __restrict__ csr_src, const int* __restrict__ batch,
         float* __restrict__ pooled) {
  __shared__ float2 red[64][9];     // pad to 9 -> max 2-way bank alias (free)
  int w = blockIdx.x;
  int h = (w & 7) >> 2;
  int sub = (w >> 3) * 4 + (w & 3);
  if (sub >= NODEBLK) return;
  const __half2* q = h ? q_hi : q_lo;
  int t = threadIdx.x;
  int fp = t & 7;           // feature half2 0..7 within plane
  int rg = t >> 3;          // node slot 0..63
  int vb = sub * 64;
  int v = vb + rg;
  int nlast = min(vb + 63, N_NODES - 1);
  bool uniform = (batch[vb] == batch[nlast]);
  float2 acc = make_float2(0.f, 0.f);
  int g = -1;
  if (v < N_NODES) {
    g = batch[v];
    int e0 = row_ptr[v], e1 = row_ptr[v + 1];
    float2 z = __half22float2(q[v * 8 + fp]);
    int k = e0;
    int u0, u1, u2, u3, u4, u5, u6, u7;
    bool have = (k + 8 <= e1);
    if (have) {
      u0 = csr_src[k];     u1 = csr_src[k + 1]; u2 = csr_src[k + 2]; u3 = csr_src[k + 3];
      u4 = csr_src[k + 4]; u5 = csr_src[k + 5]; u6 = csr_src[k + 6]; u7 = csr_src[k + 7];
    }
    while (have) {
      int n0, n1, n2, n3, n4, n5, n6, n7;
      bool nxt = (k + 16 <= e1);
      if (nxt) {
        n0 = csr_src[k + 8];  n1 = csr_src[k + 9];  n2 = csr_src[k + 10]; n3 = csr_src[k + 11];
        n4 = csr_src[k + 12]; n5 = csr_src[k + 13]; n6 = csr_src[k + 14]; n7 = csr_src[k + 15];
      }
      float2 f0 = __half22float2(q[u0 * 8 + fp]);
      float2 f1 = __half22float2(q[u1 * 8 + fp]);
      float2 f2 = __half22float2(q[u2 * 8 + fp]);
      float2 f3 = __half22float2(q[u3 * 8 + fp]);
      float2 f4 = __half22float2(q[u4 * 8 + fp]);
      float2 f5 = __half22float2(q[u5 * 8 + fp]);
      float2 f6 = __half22float2(q[u6 * 8 + fp]);
      float2 f7 = __half22float2(q[u7 * 8 + fp]);
      z.x += ((f0.x + f1.x) + (f2.x + f3.x)) + ((f4.x + f5.x) + (f6.x + f7.x));
      z.y += ((f0.y + f1.y) + (f2.y + f3.y)) + ((f4.y + f5.y) + (f6.y + f7.y));
      k += 8;
      u0 = n0; u1 = n1; u2 = n2; u3 = n3; u4 = n4; u5 = n5; u6 = n6; u7 = n7;
      have = nxt;
    }
    for (; k < e1; ++k) {
      float2 f = __half22float2(q[csr_src[k] * 8 + fp]);
      z.x += f.x;
      z.y += f.y;
    }
    float dvv = dis[v];
    acc = make_float2(z.x * dvv, z.y * dvv);
  }
  if (uniform) {
    red[rg][fp] = acc;
    __syncthreads();
    if (t < 8) {
      float2 ssum = make_float2(0.f, 0.f);
#pragma unroll
      for (int r = 0; r < 64; ++r) {
        float2 x2 = red[r][t];
        ssum.x += x2.x;
        ssum.y += x2.y;
      }
      int gg = batch[vb];
      atomicAdd(&pooled[gg * 32 + h * 16 + 2 * t], ssum.x);
      atomicAdd(&pooled[gg * 32 + h * 16 + 2 * t + 1], ssum.y);
    }
  } else if (v < N_NODES) {
    atomicAdd(&pooled[g * 32 + h * 16 + 2 * fp], acc.x);
    atomicAdd(&pooled[g * 32 + h * 16 + 2 * fp + 1], acc.y);
  }
}

// ---------- final: mean + b2 ----------
__global__ void k_final(float* __restrict__ out, const int* __restrict__ gstart,
                        const float* __restrict__ b2) {
  int i = blockIdx.x * 256 + threadIdx.x;
  if (i < N_GRAPHS * 32) {
    int g = i >> 5, l = i & 31;
    int c = gstart[g + 1] - gstart[g];
    out[i] = (c > 0) ? out[i] / (float)c + b2[l] : 0.f;
  }
}

extern "C" void kernel_launch(void* const* d_in, const int* in_sizes, int n_in,
                              void* d_out, int out_size, void* d_ws, size_t ws_size,
                              hipStream_t stream) {
  (void)in_sizes; (void)n_in; (void)out_size; (void)ws_size;
  const float* x   = (const float*)d_in[0];
  const float* W1  = (const float*)d_in[1];
  const float* b1  = (const float*)d_in[2];
  const float* W2  = (const float*)d_in[3];
  const float* b2  = (const float*)d_in[4];
  const int* edge  = (const int*)d_in[5];
  const int* batch = (const int*)d_in[6];
  const int* src = edge;             // edge_index[0]
  const int* dst = edge + N_EDGES;   // edge_index[1]
  float* out = (float*)d_out;

  int* ws      = (int*)d_ws;
  int* gstart  = ws + OFF_GSTART;
  int* row_ptr = ws + OFF_ROWPTR;
  float* dis   = (float*)(ws + OFF_DIS);
  float2* s    = (float2*)(ws + OFF_S);
  int* csr_src = ws + OFF_CSR;
  int4* q_lo4  = (int4*)(ws + OFF_QLO);
  int4* q_hi4  = (int4*)(ws + OFF_QHI);
  int* bhist   = ws + OFF_BHIST;
  int* boffl   = ws + OFF_BOFFL;
  int* bsum    = ws + OFF_BSUM;
  int* bstart  = ws + OFF_BSTART;
  int* tmp     = ws + OFF_TMP;

  k_hist<<<NBLK, 256, 0, stream>>>(dst, bhist);
  k_scan_a<<<NBUCK, 256, 0, stream>>>(bhist, boffl, bsum, batch, gstart);
  k_scan_b<<<1, 512, 0, stream>>>(bsum, bstart, out);
  k_scatter<<<NBLK, 256, 0, stream>>>(src, dst, bstart, boffl, tmp);
  k_fine<<<NBUCK, 256, 0, stream>>>(tmp, bstart, x, csr_src, row_ptr, dis, s);
  k_layer1<<<(N_NODES + 255) / 256, 256, 0, stream>>>(s, dis, row_ptr, csr_src,
                                                      W1, b1, W2, q_lo4, q_hi4);
  const int n_wg2 = ((NODEBLK + 3) / 4) * 8;   // 3128
  k_layer2<<<n_wg2, 512, 0, stream>>>((const __half2*)q_lo4, (const __half2*)q_hi4,
                                      dis, row_ptr, csr_src, batch, out);
  k_final<<<8, 256, 0, stream>>>(out, gstart, b2);
}

// Round 8
// 97.156 us; speedup vs baseline: 4.4490x; 1.1692x over previous
//
#include <hip/hip_runtime.h>
#include <hip/hip_fp16.h>

#define N_NODES  100000
#define N_EDGES  1600000
#define N_GRAPHS 64
#define NBUCK    391                 // ceil(N_NODES / 256)
#define NBLK     256
#define CHUNK    (N_EDGES / NBLK)    // 6250 exactly
#define NODEBLK  1563                // ceil(N_NODES / 64)

// ---- workspace layout (int elements). q (fp8, 800K ints) overlays the sort
// scratch, which is dead after k_fine. Max extent 3,802,112 ints = 15.2 MB.
#define OFF_GSTART 0            // 65 -> pad 128
#define OFF_ROWPTR 128          // 100,001 -> pad 100,096
#define OFF_DIS    100224       // 100,000 -> pad 100,096
#define OFF_S      200320       // 200,000 (8B aligned) -> pad 200,064
#define OFF_CSR    400384       // 1,600,000
#define OFF_Q      2000384      // 800,000 ints (100k x 8 dwords of fp8)
#define OFF_BHIST  2000384      // overlays Q (dead after k_scan_a; q written later)
#define OFF_BOFFL  2100736      // 100,352
#define OFF_BSUM   2201088      // 391 -> pad 512
#define OFF_BSTART 2201600      // 392 -> pad 512
#define OFF_TMP    2202112      // 1,600,000 (dead after k_fine)

typedef float fvec2 __attribute__((ext_vector_type(2)));

// ---------- scan helpers (block-uniform call sites only) ----------
__device__ __forceinline__ int excl_scan_256(int v, int* wsum) {
  int t = threadIdx.x, lane = t & 63, w = t >> 6;
  int x = v;
#pragma unroll
  for (int off = 1; off < 64; off <<= 1) {
    int y = __shfl_up(x, off, 64);
    if (lane >= off) x += y;
  }
  if (lane == 63) wsum[w] = x;
  __syncthreads();
  if (t == 0) {
    int r = 0;
#pragma unroll
    for (int i = 0; i < 4; ++i) { int tv = wsum[i]; wsum[i] = r; r += tv; }
  }
  __syncthreads();
  return x - v + wsum[w];
}

__device__ __forceinline__ int excl_scan_512(int v, int* wsum) {
  int t = threadIdx.x, lane = t & 63, w = t >> 6;
  int x = v;
#pragma unroll
  for (int off = 1; off < 64; off <<= 1) {
    int y = __shfl_up(x, off, 64);
    if (lane >= off) x += y;
  }
  if (lane == 63) wsum[w] = x;
  __syncthreads();
  if (t == 0) {
    int r = 0;
#pragma unroll
    for (int i = 0; i < 8; ++i) { int tv = wsum[i]; wsum[i] = r; r += tv; }
  }
  __syncthreads();
  return x - v + wsum[w];
}

// ---------- pass 1: per-block coarse histogram (LDS atomics only) ----------
__global__ void k_hist(const int* __restrict__ dst, int* __restrict__ bhist) {
  __shared__ int hist[NBUCK];
  int t = threadIdx.x, k = blockIdx.x;
  for (int b = t; b < NBUCK; b += 256) hist[b] = 0;
  __syncthreads();
  int e0 = k * CHUNK, e1 = e0 + CHUNK;
  for (int e = e0 + t; e < e1; e += 256) atomicAdd(&hist[dst[e] >> 8], 1);
  __syncthreads();
  for (int b = t; b < NBUCK; b += 256) bhist[b * NBLK + k] = hist[b];
}

// ---------- pass 2a: scan each bucket's per-block counts + graph bounds ----
__global__ void k_scan_a(const int* __restrict__ bhist, int* __restrict__ boffl,
                         int* __restrict__ bsum, const int* __restrict__ batch,
                         int* __restrict__ gstart) {
  __shared__ int wsum[4];
  int t = threadIdx.x, b = blockIdx.x;
  int i = b * 256 + t;
  if (i < N_NODES) {
    int bi = batch[i];
    if (i == 0) {
      for (int g = 0; g <= bi; ++g) gstart[g] = 0;
    } else {
      int bp = batch[i - 1];
      for (int g = bp + 1; g <= bi; ++g) gstart[g] = i;
    }
    if (i == N_NODES - 1) {
      for (int g = bi + 1; g <= N_GRAPHS; ++g) gstart[g] = N_NODES;
    }
  }
  int v = bhist[b * NBLK + t];
  int ex = excl_scan_256(v, wsum);
  boffl[b * NBLK + t] = ex;
  if (t == NBLK - 1) bsum[b] = ex + v;
}

// ---------- pass 2b: scan bucket totals -> bstart; zero pooled output ------
__global__ void k_scan_b(const int* __restrict__ bsum, int* __restrict__ bstart,
                         float* __restrict__ pooled) {
  __shared__ int wsum[8];
  int t = threadIdx.x;
  for (int i = t; i < N_GRAPHS * 32; i += 512) pooled[i] = 0.f;
  int v = (t < NBUCK) ? bsum[t] : 0;
  int ex = excl_scan_512(v, wsum);
  if (t <= NBUCK) bstart[t] = ex;
}

// ---------- pass 3: scatter edges into coarse buckets (LDS atomics only) ----
__global__ void k_scatter(const int* __restrict__ src, const int* __restrict__ dst,
                          const int* __restrict__ bstart, const int* __restrict__ boffl,
                          int* __restrict__ tmp) {
  __shared__ int sbase[NBUCK];
  __shared__ int fill[NBUCK];
  int t = threadIdx.x, k = blockIdx.x;
  for (int b = t; b < NBUCK; b += 256) {
    sbase[b] = bstart[b] + boffl[b * NBLK + k];
    fill[b] = 0;
  }
  __syncthreads();
  int e0 = k * CHUNK, e1 = e0 + CHUNK;
  for (int e = e0 + t; e < e1; e += 256) {
    int s_ = src[e], d_ = dst[e];
    int b = d_ >> 8;
    int pos = sbase[b] + atomicAdd(&fill[b], 1);
    tmp[pos] = (s_ << 8) | (d_ & 255);
  }
}

// ---------- pass 4: per-bucket fine CSR + dis + s (LDS atomics only) -------
__global__ void k_fine(const int* __restrict__ tmp, const int* __restrict__ bstart,
                       const float* __restrict__ x, int* __restrict__ csr_src,
                       int* __restrict__ row_ptr, float* __restrict__ dis,
                       float2* __restrict__ s) {
  __shared__ int hist[256];   // becomes scanned offsets after scan
  __shared__ int fill[256];
  __shared__ int wsum[4];
  int t = threadIdx.x, b = blockIdx.x;
  int base_n = b << 8;
  int e0 = bstart[b], e1 = bstart[b + 1];
  hist[t] = 0;
  __syncthreads();
  for (int e = e0 + t; e < e1; e += 256) atomicAdd(&hist[tmp[e] & 255], 1);
  __syncthreads();
  int h = hist[t];
  int ex = excl_scan_256(h, wsum);
  hist[t] = ex;
  fill[t] = 0;
  int nn = min(256, N_NODES - base_n);
  if (t < nn) {
    int v = base_n + t;
    row_ptr[v] = e0 + ex;
    float dv = rsqrtf((float)(h + 1));
    dis[v] = dv;
    float2 xv = ((const float2*)x)[v];
    s[v] = make_float2(xv.x * dv, xv.y * dv);
  }
  if (b == NBUCK - 1 && t == 0) row_ptr[N_NODES] = e1;
  __syncthreads();
  for (int e = e0 + t; e < e1; e += 256) {
    int p = tmp[e];
    int fine = p & 255;
    int pos = e0 + hist[fine] + atomicAdd(&fill[fine], 1);
    csr_src[pos] = p >> 8;
  }
}

// ---------- layer 1 fused: t = dis*(sum s + self); q = fp8(dis*relu(t@W1+b1)@W2)
// weights as float4 LDS broadcasts (proven best config); output one fp8 row
// of 32 bytes per node (8 dwords).
__global__ void k_layer1(const float2* __restrict__ s, const float* __restrict__ dis,
                         const int* __restrict__ row_ptr, const int* __restrict__ csr_src,
                         const float* __restrict__ W1, const float* __restrict__ b1,
                         const float* __restrict__ W2, int4* __restrict__ q8) {
  __shared__ float4 sWB[64];     // {W1[0][j], W1[1][j], b1[j], 0}
  __shared__ float4 sW2[512];    // W2 row-major as float4
  int tid = threadIdx.x;
  if (tid < 64) sWB[tid] = make_float4(W1[tid], W1[64 + tid], b1[tid], 0.f);
  for (int i = tid; i < 512; i += 256) sW2[i] = ((const float4*)W2)[i];
  __syncthreads();
  int v = blockIdx.x * 256 + tid;
  if (v >= N_NODES) return;
  int beg = row_ptr[v], end = row_ptr[v + 1];
  float2 sv = s[v];
  float t0 = sv.x, t1 = sv.y;
  int k = beg;
  for (; k + 4 <= end; k += 4) {
    int u0 = csr_src[k], u1 = csr_src[k + 1], u2 = csr_src[k + 2], u3 = csr_src[k + 3];
    float2 a = s[u0], b = s[u1], c = s[u2], d = s[u3];
    t0 += (a.x + b.x) + (c.x + d.x);
    t1 += (a.y + b.y) + (c.y + d.y);
  }
  for (; k < end; ++k) {
    float2 su = s[csr_src[k]];
    t0 += su.x;
    t1 += su.y;
  }
  float dv = dis[v];
  t0 *= dv;
  t1 *= dv;
  float4 a4[8];
#pragma unroll
  for (int m = 0; m < 8; ++m) a4[m] = make_float4(0.f, 0.f, 0.f, 0.f);
  for (int j = 0; j < 64; ++j) {
    float4 wb = sWB[j];
    float r = fmaxf(fmaf(t0, wb.x, fmaf(t1, wb.y, wb.z)), 0.f);
#pragma unroll
    for (int m = 0; m < 8; ++m) {
      float4 w = sW2[j * 8 + m];
      a4[m].x = fmaf(r, w.x, a4[m].x);
      a4[m].y = fmaf(r, w.y, a4[m].y);
      a4[m].z = fmaf(r, w.z, a4[m].z);
      a4[m].w = fmaf(r, w.w, a4[m].w);
    }
  }
  int pk[8];
#pragma unroll
  for (int m = 0; m < 8; ++m) {
    int wrd = __builtin_amdgcn_cvt_pk_fp8_f32(a4[m].x * dv, a4[m].y * dv, 0, false);
    wrd = __builtin_amdgcn_cvt_pk_fp8_f32(a4[m].z * dv, a4[m].w * dv, wrd, true);
    pk[m] = wrd;
  }
  q8[v * 2]     = make_int4(pk[0], pk[1], pk[2], pk[3]);
  q8[v * 2 + 1] = make_int4(pk[4], pk[5], pk[6], pk[7]);
}

// ---------- layer 2 + pooling: single fp8 q table (3.2 MB, L2-fits per XCD).
// 256 thr: 32 rowgroups x 8 lanes; lane = feature-dword (4 fp8 feats); 2 nodes
// per rowgroup; 8-deep unrolled gather (R3-proven geometry, halved requests).
__device__ __forceinline__ float4 qdec(unsigned int d) {
  fvec2 lo = __builtin_amdgcn_cvt_pk_f32_fp8(d, false);
  fvec2 hi = __builtin_amdgcn_cvt_pk_f32_fp8(d, true);
  return make_float4(lo.x, lo.y, hi.x, hi.y);
}

__global__ void k_layer2(const unsigned int* __restrict__ q, const float* __restrict__ dis,
                         const int* __restrict__ row_ptr, const int* __restrict__ csr_src,
                         const int* __restrict__ batch, float* __restrict__ pooled) {
  __shared__ float4 red[32][9];    // pad 9 to spread banks
  int t = threadIdx.x;
  int fp = t & 7;           // feature dword 0..7 (4 features each)
  int rg = t >> 3;          // rowgroup 0..31
  int vb = blockIdx.x * 64;
  int nlast = min(vb + 63, N_NODES - 1);
  bool uniform = (batch[vb] == batch[nlast]);
  int v0 = vb + rg * 2;
  int v1 = min(v0 + 2, N_NODES);
  float4 acc = make_float4(0.f, 0.f, 0.f, 0.f);
  int curg = (v0 < N_NODES) ? batch[v0] : -1;
  for (int v = v0; v < v1; ++v) {
    if (!uniform) {
      int g = batch[v];
      if (g != curg) {
        int base = curg * 32 + fp * 4;
        atomicAdd(&pooled[base],     acc.x);
        atomicAdd(&pooled[base + 1], acc.y);
        atomicAdd(&pooled[base + 2], acc.z);
        atomicAdd(&pooled[base + 3], acc.w);
        acc = make_float4(0.f, 0.f, 0.f, 0.f);
        curg = g;
      }
    }
    int e0 = row_ptr[v], e1 = row_ptr[v + 1];
    float4 z = qdec(q[v * 8 + fp]);
    int k = e0;
    for (; k + 8 <= e1; k += 8) {
      int u0 = csr_src[k],     u1 = csr_src[k + 1], u2 = csr_src[k + 2], u3 = csr_src[k + 3];
      int u4 = csr_src[k + 4], u5 = csr_src[k + 5], u6 = csr_src[k + 6], u7 = csr_src[k + 7];
      float4 f0 = qdec(q[u0 * 8 + fp]);
      float4 f1 = qdec(q[u1 * 8 + fp]);
      float4 f2 = qdec(q[u2 * 8 + fp]);
      float4 f3 = qdec(q[u3 * 8 + fp]);
      float4 f4 = qdec(q[u4 * 8 + fp]);
      float4 f5 = qdec(q[u5 * 8 + fp]);
      float4 f6 = qdec(q[u6 * 8 + fp]);
      float4 f7 = qdec(q[u7 * 8 + fp]);
      z.x += ((f0.x + f1.x) + (f2.x + f3.x)) + ((f4.x + f5.x) + (f6.x + f7.x));
      z.y += ((f0.y + f1.y) + (f2.y + f3.y)) + ((f4.y + f5.y) + (f6.y + f7.y));
      z.z += ((f0.z + f1.z) + (f2.z + f3.z)) + ((f4.z + f5.z) + (f6.z + f7.z));
      z.w += ((f0.w + f1.w) + (f2.w + f3.w)) + ((f4.w + f5.w) + (f6.w + f7.w));
    }
    for (; k < e1; ++k) {
      float4 f = qdec(q[csr_src[k] * 8 + fp]);
      z.x += f.x; z.y += f.y; z.z += f.z; z.w += f.w;
    }
    float dvv = dis[v];
    acc.x = fmaf(z.x, dvv, acc.x);
    acc.y = fmaf(z.y, dvv, acc.y);
    acc.z = fmaf(z.z, dvv, acc.z);
    acc.w = fmaf(z.w, dvv, acc.w);
  }
  if (uniform) {
    red[rg][fp] = acc;
    __syncthreads();
    if (t < 8) {
      float4 ssum = make_float4(0.f, 0.f, 0.f, 0.f);
#pragma unroll
      for (int r = 0; r < 32; ++r) {
        float4 x4 = red[r][t];
        ssum.x += x4.x; ssum.y += x4.y; ssum.z += x4.z; ssum.w += x4.w;
      }
      int gg = batch[vb];
      int base = gg * 32 + t * 4;
      atomicAdd(&pooled[base],     ssum.x);
      atomicAdd(&pooled[base + 1], ssum.y);
      atomicAdd(&pooled[base + 2], ssum.z);
      atomicAdd(&pooled[base + 3], ssum.w);
    }
  } else if (v0 < N_NODES) {
    int base = curg * 32 + fp * 4;
    atomicAdd(&pooled[base],     acc.x);
    atomicAdd(&pooled[base + 1], acc.y);
    atomicAdd(&pooled[base + 2], acc.z);
    atomicAdd(&pooled[base + 3], acc.w);
  }
}

// ---------- final: mean + b2 ----------
__global__ void k_final(float* __restrict__ out, const int* __restrict__ gstart,
                        const float* __restrict__ b2) {
  int i = blockIdx.x * 256 + threadIdx.x;
  if (i < N_GRAPHS * 32) {
    int g = i >> 5, l = i & 31;
    int c = gstart[g + 1] - gstart[g];
    out[i] = (c > 0) ? out[i] / (float)c + b2[l] : 0.f;
  }
}

extern "C" void kernel_launch(void* const* d_in, const int* in_sizes, int n_in,
                              void* d_out, int out_size, void* d_ws, size_t ws_size,
                              hipStream_t stream) {
  (void)in_sizes; (void)n_in; (void)out_size; (void)ws_size;
  const float* x   = (const float*)d_in[0];
  const float* W1  = (const float*)d_in[1];
  const float* b1  = (const float*)d_in[2];
  const float* W2  = (const float*)d_in[3];
  const float* b2  = (const float*)d_in[4];
  const int* edge  = (const int*)d_in[5];
  const int* batch = (const int*)d_in[6];
  const int* src = edge;             // edge_index[0]
  const int* dst = edge + N_EDGES;   // edge_index[1]
  float* out = (float*)d_out;

  int* ws      = (int*)d_ws;
  int* gstart  = ws + OFF_GSTART;
  int* row_ptr = ws + OFF_ROWPTR;
  float* dis   = (float*)(ws + OFF_DIS);
  float2* s    = (float2*)(ws + OFF_S);
  int* csr_src = ws + OFF_CSR;
  int4* q8     = (int4*)(ws + OFF_Q);
  int* bhist   = ws + OFF_BHIST;
  int* boffl   = ws + OFF_BOFFL;
  int* bsum    = ws + OFF_BSUM;
  int* bstart  = ws + OFF_BSTART;
  int* tmp     = ws + OFF_TMP;

  k_hist<<<NBLK, 256, 0, stream>>>(dst, bhist);
  k_scan_a<<<NBUCK, 256, 0, stream>>>(bhist, boffl, bsum, batch, gstart);
  k_scan_b<<<1, 512, 0, stream>>>(bsum, bstart, out);
  k_scatter<<<NBLK, 256, 0, stream>>>(src, dst, bstart, boffl, tmp);
  k_fine<<<NBUCK, 256, 0, stream>>>(tmp, bstart, x, csr_src, row_ptr, dis, s);
  k_layer1<<<(N_NODES + 255) / 256, 256, 0, stream>>>(s, dis, row_ptr, csr_src,
                                                      W1, b1, W2, q8);
  k_layer2<<<NODEBLK, 256, 0, stream>>>((const unsigned int*)q8, dis, row_ptr,
                                        csr_src, batch, out);
  k_final<<<8, 256, 0, stream>>>(out, gstart, b2);
}